// Round 1
// baseline (1460.498 us; speedup 1.0000x reference)
//
#include <hip/hip_runtime.h>

// ---------------------------------------------------------------------------
// BLSTM: emb gather -> fwd LSTM scan + bwd single-step -> [2048,512] @ fc_w^T
// B=16 S=128 V=32000 D=H=256.  Output logits [16,128,32000] fp32.
// ---------------------------------------------------------------------------

#define Bz 16
#define Sq 128
#define Vv 32000
#define Dd 256
#define Hh 256
#define Mrows (Bz * Sq)        // 2048
#define Ktot  (2 * Hh)         // 512

typedef __bf16 bf16x8 __attribute__((ext_vector_type(8)));
typedef float  f32x4  __attribute__((ext_vector_type(4)));

__device__ __forceinline__ unsigned short f2bf(float x) {
  union { float f; unsigned u; } v; v.f = x;
  unsigned r = (v.u + 0x7FFFu + ((v.u >> 16) & 1u)) >> 16;
  return (unsigned short)r;
}
__device__ __forceinline__ float sigm(float x) { return 1.f / (1.f + __expf(-x)); }
__device__ __forceinline__ float tanh_(float x) { return 2.f / (1.f + __expf(-2.f * x)) - 1.f; }
__device__ __forceinline__ void fma4(float4& a, const float4 w, const float s) {
  a.x = fmaf(w.x, s, a.x); a.y = fmaf(w.y, s, a.y);
  a.z = fmaf(w.z, s, a.z); a.w = fmaf(w.w, s, a.w);
}

// --------------------------------------------------------------------------
// K0: transpose+pack recurrent/input weights to [k][j] float4 (i,f,g,o) and
// fold biases.  grid (256, 3), block 256.
// --------------------------------------------------------------------------
__global__ __launch_bounds__(256) void k0_pack(
    const float* __restrict__ w_ih_f, const float* __restrict__ w_hh_f,
    const float* __restrict__ w_ih_b,
    const float* __restrict__ b_ih_f, const float* __restrict__ b_hh_f,
    const float* __restrict__ b_ih_b, const float* __restrict__ b_hh_b,
    float4* __restrict__ wPackF, float4* __restrict__ wPackB,
    float4* __restrict__ wPackH, float4* __restrict__ biasF,
    float4* __restrict__ biasB)
{
  const int j = threadIdx.x;   // output column 0..255
  const int k = blockIdx.x;    // input dim 0..255
  const int g = blockIdx.y;    // 0: w_ih_f, 1: w_ih_b, 2: w_hh_f
  const float* src = (g == 0) ? w_ih_f : ((g == 1) ? w_ih_b : w_hh_f);
  float4* dst = (g == 0) ? wPackF : ((g == 1) ? wPackB : wPackH);
  float4 v;
  v.x = src[(j      ) * 256 + k];
  v.y = src[(j + 256) * 256 + k];
  v.z = src[(j + 512) * 256 + k];
  v.w = src[(j + 768) * 256 + k];
  dst[k * 256 + j] = v;
  if (k == 0 && g == 0) {
    float4 b;
    b.x = b_ih_f[j      ] + b_hh_f[j      ];
    b.y = b_ih_f[j + 256] + b_hh_f[j + 256];
    b.z = b_ih_f[j + 512] + b_hh_f[j + 512];
    b.w = b_ih_f[j + 768] + b_hh_f[j + 768];
    biasF[j] = b;
  }
  if (k == 0 && g == 1) {
    float4 b;
    b.x = b_ih_b[j      ] + b_hh_b[j      ];
    b.y = b_ih_b[j + 256] + b_hh_b[j + 256];
    b.z = b_ih_b[j + 512] + b_hh_b[j + 512];
    b.w = b_ih_b[j + 768] + b_hh_b[j + 768];
    biasB[j] = b;
  }
}

// --------------------------------------------------------------------------
// K1: embedding gather + input projections. grid (128, 2): y=0 -> xpPack
// (fwd, with biases folded), y=1 -> backward single-step cell -> hb (bf16,
// right half of the GEMM A matrix). 16 rows per block, 256 threads.
// --------------------------------------------------------------------------
__global__ __launch_bounds__(256) void k1_embproj(
    const int* __restrict__ x, const float* __restrict__ embed,
    const float4* __restrict__ wPackF, const float4* __restrict__ wPackB,
    const float4* __restrict__ biasF, const float4* __restrict__ biasB,
    float4* __restrict__ xpPack, unsigned short* __restrict__ outB)
{
  __shared__ __align__(16) float e[16][256];
  __shared__ int xi[16];
  const int j = threadIdx.x;
  const int m0 = blockIdx.x * 16;
  const int dir = blockIdx.y;
  if (j < 16) xi[j] = x[m0 + j];
  __syncthreads();
#pragma unroll
  for (int m = 0; m < 16; ++m) e[m][j] = embed[(size_t)xi[m] * Dd + j];
  __syncthreads();

  const float4* wP = dir ? wPackB : wPackF;
  float4 acc[16];
#pragma unroll
  for (int m = 0; m < 16; ++m) acc[m] = make_float4(0.f, 0.f, 0.f, 0.f);

  for (int k = 0; k < 256; k += 4) {
    const float4 w0 = wP[(k + 0) * 256 + j];
    const float4 w1 = wP[(k + 1) * 256 + j];
    const float4 w2 = wP[(k + 2) * 256 + j];
    const float4 w3 = wP[(k + 3) * 256 + j];
#pragma unroll
    for (int m = 0; m < 16; ++m) {
      const float4 e4 = *(const float4*)&e[m][k];
      fma4(acc[m], w0, e4.x); fma4(acc[m], w1, e4.y);
      fma4(acc[m], w2, e4.z); fma4(acc[m], w3, e4.w);
    }
  }

  if (dir == 0) {
    const float4 bv = biasF[j];
#pragma unroll
    for (int m = 0; m < 16; ++m) {
      float4 v = acc[m];
      v.x += bv.x; v.y += bv.y; v.z += bv.z; v.w += bv.w;
      xpPack[(m0 + m) * 256 + j] = v;
    }
  } else {
    const float4 bv = biasB[j];
#pragma unroll
    for (int m = 0; m < 16; ++m) {
      float4 v = acc[m];
      v.x += bv.x; v.y += bv.y; v.z += bv.z; v.w += bv.w;
      const float ig = sigm(v.x);
      const float gg = tanh_(v.z);
      const float og = sigm(v.w);
      const float hb = og * tanh_(ig * gg);
      outB[(size_t)(m0 + m) * Ktot + Hh + j] = f2bf(hb);
    }
  }
}

// --------------------------------------------------------------------------
// K2: forward LSTM scan.  One block per batch element; thread j owns h[j],
// c[j] and gate columns (j, j+256, j+512, j+768).  h broadcast via LDS.
// --------------------------------------------------------------------------
__global__ __launch_bounds__(256) void k2_scan(
    const float4* __restrict__ xpPack, const float4* __restrict__ wPackH,
    unsigned short* __restrict__ outB)
{
  __shared__ __align__(16) float h[256];
  const int j = threadIdx.x;
  const int b = blockIdx.x;
  float c = 0.f;
  h[j] = 0.f;
  __syncthreads();
  for (int t = 0; t < Sq; ++t) {
    float4 acc = xpPack[(b * Sq + t) * 256 + j];
#pragma unroll 2
    for (int k = 0; k < 256; k += 4) {
      const float4 h4 = *(const float4*)&h[k];
      const float4 w0 = wPackH[(k + 0) * 256 + j];
      const float4 w1 = wPackH[(k + 1) * 256 + j];
      const float4 w2 = wPackH[(k + 2) * 256 + j];
      const float4 w3 = wPackH[(k + 3) * 256 + j];
      fma4(acc, w0, h4.x); fma4(acc, w1, h4.y);
      fma4(acc, w2, h4.z); fma4(acc, w3, h4.w);
    }
    const float ig = sigm(acc.x);
    const float fg = sigm(acc.y);
    const float gg = tanh_(acc.z);
    const float og = sigm(acc.w);
    c = fg * c + ig * gg;
    const float hn = og * tanh_(c);
    __syncthreads();
    h[j] = hn;
    outB[(size_t)(b * Sq + t) * Ktot + j] = f2bf(hn);
    __syncthreads();
  }
}

// --------------------------------------------------------------------------
// K3: fc_w fp32 -> bf16.  16,384,000 elems; 4 per thread.
// --------------------------------------------------------------------------
__global__ __launch_bounds__(256) void k3_cvt(const float4* __restrict__ s,
                                              uint2* __restrict__ d)
{
  const int i = blockIdx.x * 256 + threadIdx.x;
  const float4 v = s[i];
  uint2 r;
  r.x = (unsigned)f2bf(v.x) | ((unsigned)f2bf(v.y) << 16);
  r.y = (unsigned)f2bf(v.z) | ((unsigned)f2bf(v.w) << 16);
  d[i] = r;
}

// --------------------------------------------------------------------------
// K4: logits = [2048,512](bf16) x fc_w^T (fc_w [32000,512] bf16, B^T layout)
// + fc_b.  128x128 tile, BK=64, 4 waves (each 64x64 = 4x4 MFMA tiles),
// global_load_lds width-16 staging (m97 structure).
// grid (16, 250): consecutive blockIdx.x share the B n-tile (L2 reuse).
// --------------------------------------------------------------------------
__device__ __forceinline__ void load_lds_16(const void* g, void* l) {
  __builtin_amdgcn_global_load_lds(
      (const __attribute__((address_space(1))) unsigned int*)g,
      (__attribute__((address_space(3))) unsigned int*)l, 16, 0, 0);
}

__global__ __launch_bounds__(256) void k4_gemm(
    const unsigned short* __restrict__ A,   // [2048][512] bf16
    const unsigned short* __restrict__ Bm,  // [32000][512] bf16
    const float* __restrict__ fcb,          // [32000]
    float* __restrict__ out)                // [2048][32000]
{
  __shared__ __align__(16) char smem[32768];  // As [0,16K), Bs [16K,32K)
  const int tid  = threadIdx.x;
  const int wave = tid >> 6;
  const int lane = tid & 63;
  const int bm = blockIdx.x;      // 0..15  (M tiles)
  const int bn = blockIdx.y;      // 0..249 (N tiles)
  const int wm = (wave >> 1) * 64;
  const int wn = (wave & 1) * 64;
  const int quad = lane >> 4;
  const int r16  = lane & 15;

  f32x4 acc[4][4] = {};

  // staging addresses: thread covers row (r*32 + tid/8), col (tid%8)*8..+7
  const unsigned short* Ag = A  + ((size_t)(bm * 128) + (tid >> 3)) * Ktot + (tid & 7) * 8;
  const unsigned short* Bg = Bm + ((size_t)(bn * 128) + (tid >> 3)) * Ktot + (tid & 7) * 8;
  char* AsW = smem + wave * 1024;           // wave-uniform LDS bases
  char* BsW = smem + 16384 + wave * 1024;

  for (int kt = 0; kt < 8; ++kt) {
    const int k0 = kt * 64;
#pragma unroll
    for (int r = 0; r < 4; ++r) {
      load_lds_16(Ag + (size_t)r * 32 * Ktot + k0, AsW + r * 4096);
      load_lds_16(Bg + (size_t)r * 32 * Ktot + k0, BsW + r * 4096);
    }
    __syncthreads();
#pragma unroll
    for (int kk = 0; kk < 2; ++kk) {
      bf16x8 af[4], bfr[4];
#pragma unroll
      for (int i = 0; i < 4; ++i) {
        const int rowA = wm + i * 16 + r16;
        af[i] = *(const bf16x8*)(smem + rowA * 128 + kk * 64 + quad * 16);
        const int rowB = wn + i * 16 + r16;
        bfr[i] = *(const bf16x8*)(smem + 16384 + rowB * 128 + kk * 64 + quad * 16);
      }
#pragma unroll
      for (int i = 0; i < 4; ++i)
#pragma unroll
        for (int j = 0; j < 4; ++j)
          acc[i][j] = __builtin_amdgcn_mfma_f32_16x16x32_bf16(af[i], bfr[j], acc[i][j], 0, 0, 0);
    }
    __syncthreads();
  }

  // epilogue: D[row=quad*4+r][col=lane&15] per 16x16 tile
#pragma unroll
  for (int j = 0; j < 4; ++j) {
    const int col = bn * 128 + wn + j * 16 + r16;
    const float bias = fcb[col];
#pragma unroll
    for (int i = 0; i < 4; ++i) {
      const int row0 = bm * 128 + wm + i * 16 + quad * 4;
#pragma unroll
      for (int r = 0; r < 4; ++r) {
        out[(size_t)(row0 + r) * Vv + col] = acc[i][j][r] + bias;
      }
    }
  }
}

// --------------------------------------------------------------------------
extern "C" void kernel_launch(void* const* d_in, const int* in_sizes, int n_in,
                              void* d_out, int out_size, void* d_ws, size_t ws_size,
                              hipStream_t stream) {
  const int*   x      = (const int*)d_in[0];
  const float* embed  = (const float*)d_in[1];
  const float* w_ih_f = (const float*)d_in[2];
  const float* w_hh_f = (const float*)d_in[3];
  const float* b_ih_f = (const float*)d_in[4];
  const float* b_hh_f = (const float*)d_in[5];
  const float* w_ih_b = (const float*)d_in[6];
  // d_in[7] = w_hh_b: unused (backward direction is a zero-state single step)
  const float* b_ih_b = (const float*)d_in[8];
  const float* b_hh_b = (const float*)d_in[9];
  const float* fc_w   = (const float*)d_in[10];
  const float* fc_b   = (const float*)d_in[11];
  float* out = (float*)d_out;

  char* ws = (char*)d_ws;
  float4* wPackF = (float4*)(ws + 0x000000);           // 1 MB
  float4* wPackB = (float4*)(ws + 0x100000);           // 1 MB
  float4* wPackH = (float4*)(ws + 0x200000);           // 1 MB
  float4* biasF  = (float4*)(ws + 0x300000);           // 4 KB
  float4* biasB  = (float4*)(ws + 0x301000);           // 4 KB
  float4* xpPack = (float4*)(ws + 0x302000);           // 8 MB
  unsigned short* outB = (unsigned short*)(ws + 0xB02000);   // 2 MB [2048][512]
  unsigned short* fcwB = (unsigned short*)(ws + 0xD02000);   // 31.25 MB [32000][512]

  k0_pack<<<dim3(256, 3), 256, 0, stream>>>(w_ih_f, w_hh_f, w_ih_b,
                                            b_ih_f, b_hh_f, b_ih_b, b_hh_b,
                                            wPackF, wPackB, wPackH, biasF, biasB);
  k3_cvt<<<16000, 256, 0, stream>>>((const float4*)fc_w, (uint2*)fcwB);
  k1_embproj<<<dim3(128, 2), 256, 0, stream>>>(x, embed, wPackF, wPackB,
                                               biasF, biasB, xpPack, outB);
  k2_scan<<<16, 256, 0, stream>>>(xpPack, wPackH, outB);
  k4_gemm<<<dim3(16, 250), 256, 0, stream>>>(outB, fcwB, fc_b, out);
}

// Round 2
// 1101.288 us; speedup vs baseline: 1.3262x; 1.3262x over previous
//
#include <hip/hip_runtime.h>

// ---------------------------------------------------------------------------
// BLSTM: emb gather -> fwd LSTM scan + bwd single-step -> [2048,512] @ fc_w^T
// B=16 S=128 V=32000 D=H=256.  Output logits [16,128,32000] fp32.
//
// R1: k2 scan rebuilt as 64-block (16 batch x 4 hidden-slices) kernel with
// VGPR-resident W_hh rows (no in-loop weight traffic; R0 was per-CU L2-BW
// bound at 132 GB/s/CU) + agent-scope flag exchange of h between the 4
// sibling blocks each timestep.
// ---------------------------------------------------------------------------

#define Bz 16
#define Sq 128
#define Vv 32000
#define Dd 256
#define Hh 256
#define Ktot  (2 * Hh)         // 512

typedef __bf16 bf16x8 __attribute__((ext_vector_type(8)));
typedef float  f32x4  __attribute__((ext_vector_type(4)));

__device__ __forceinline__ unsigned short f2bf(float x) {
  union { float f; unsigned u; } v; v.f = x;
  unsigned r = (v.u + 0x7FFFu + ((v.u >> 16) & 1u)) >> 16;
  return (unsigned short)r;
}
__device__ __forceinline__ float sigm(float x) { return 1.f / (1.f + __expf(-x)); }
__device__ __forceinline__ float tanh_(float x) { return 2.f / (1.f + __expf(-2.f * x)) - 1.f; }
__device__ __forceinline__ void fma4(float4& a, const float4 w, const float s) {
  a.x = fmaf(w.x, s, a.x); a.y = fmaf(w.y, s, a.y);
  a.z = fmaf(w.z, s, a.z); a.w = fmaf(w.w, s, a.w);
}

// --------------------------------------------------------------------------
// k_init: zero the exchange flags (ws is poisoned 0xAA before every launch).
// --------------------------------------------------------------------------
__global__ __launch_bounds__(256) void k_init(int* __restrict__ flags) {
  for (int i = threadIdx.x; i < 16 * 132; i += 256) flags[i] = 0;
}

// --------------------------------------------------------------------------
// K0: transpose+pack input weights to [k][j] float4 (i,f,g,o), fold biases.
// grid (256, 2), block 256.
// --------------------------------------------------------------------------
__global__ __launch_bounds__(256) void k0_pack(
    const float* __restrict__ w_ih_f, const float* __restrict__ w_ih_b,
    const float* __restrict__ b_ih_f, const float* __restrict__ b_hh_f,
    const float* __restrict__ b_ih_b, const float* __restrict__ b_hh_b,
    float4* __restrict__ wPackF, float4* __restrict__ wPackB,
    float4* __restrict__ biasF, float4* __restrict__ biasB)
{
  const int j = threadIdx.x;   // output column 0..255
  const int k = blockIdx.x;    // input dim 0..255
  const int g = blockIdx.y;    // 0: w_ih_f, 1: w_ih_b
  const float* src = (g == 0) ? w_ih_f : w_ih_b;
  float4* dst = (g == 0) ? wPackF : wPackB;
  float4 v;
  v.x = src[(j      ) * 256 + k];
  v.y = src[(j + 256) * 256 + k];
  v.z = src[(j + 512) * 256 + k];
  v.w = src[(j + 768) * 256 + k];
  dst[k * 256 + j] = v;
  if (k == 0 && g == 0) {
    float4 b;
    b.x = b_ih_f[j      ] + b_hh_f[j      ];
    b.y = b_ih_f[j + 256] + b_hh_f[j + 256];
    b.z = b_ih_f[j + 512] + b_hh_f[j + 512];
    b.w = b_ih_f[j + 768] + b_hh_f[j + 768];
    biasF[j] = b;
  }
  if (k == 0 && g == 1) {
    float4 b;
    b.x = b_ih_b[j      ] + b_hh_b[j      ];
    b.y = b_ih_b[j + 256] + b_hh_b[j + 256];
    b.z = b_ih_b[j + 512] + b_hh_b[j + 512];
    b.w = b_ih_b[j + 768] + b_hh_b[j + 768];
    biasB[j] = b;
  }
}

// --------------------------------------------------------------------------
// K1: embedding gather + input projections. grid (128, 2): y=0 -> xpG
// [m][1024] gate-row-major (biases folded), y=1 -> backward single-step
// cell -> hb (bf16, right half of the GEMM A matrix).
// --------------------------------------------------------------------------
__global__ __launch_bounds__(256) void k1_embproj(
    const int* __restrict__ x, const float* __restrict__ embed,
    const float4* __restrict__ wPackF, const float4* __restrict__ wPackB,
    const float4* __restrict__ biasF, const float4* __restrict__ biasB,
    float* __restrict__ xpG, unsigned short* __restrict__ outB)
{
  __shared__ __align__(16) float e[16][256];
  __shared__ int xi[16];
  const int j = threadIdx.x;
  const int m0 = blockIdx.x * 16;
  const int dir = blockIdx.y;
  if (j < 16) xi[j] = x[m0 + j];
  __syncthreads();
#pragma unroll
  for (int m = 0; m < 16; ++m) e[m][j] = embed[(size_t)xi[m] * Dd + j];
  __syncthreads();

  const float4* wP = dir ? wPackB : wPackF;
  float4 acc[16];
#pragma unroll
  for (int m = 0; m < 16; ++m) acc[m] = make_float4(0.f, 0.f, 0.f, 0.f);

  for (int k = 0; k < 256; k += 4) {
    const float4 w0 = wP[(k + 0) * 256 + j];
    const float4 w1 = wP[(k + 1) * 256 + j];
    const float4 w2 = wP[(k + 2) * 256 + j];
    const float4 w3 = wP[(k + 3) * 256 + j];
#pragma unroll
    for (int m = 0; m < 16; ++m) {
      const float4 e4 = *(const float4*)&e[m][k];
      fma4(acc[m], w0, e4.x); fma4(acc[m], w1, e4.y);
      fma4(acc[m], w2, e4.z); fma4(acc[m], w3, e4.w);
    }
  }

  if (dir == 0) {
    const float4 bv = biasF[j];
#pragma unroll
    for (int m = 0; m < 16; ++m) {
      float4 v = acc[m];
      float* xq = xpG + (size_t)(m0 + m) * 1024 + j;
      xq[0]   = v.x + bv.x;
      xq[256] = v.y + bv.y;
      xq[512] = v.z + bv.z;
      xq[768] = v.w + bv.w;
    }
  } else {
    const float4 bv = biasB[j];
#pragma unroll
    for (int m = 0; m < 16; ++m) {
      float4 v = acc[m];
      v.x += bv.x; v.y += bv.y; v.z += bv.z; v.w += bv.w;
      const float ig = sigm(v.x);
      const float gg = tanh_(v.z);
      const float og = sigm(v.w);
      const float hb = og * tanh_(ig * gg);
      outB[(size_t)(m0 + m) * Ktot + Hh + j] = f2bf(hb);
    }
  }
}

// --------------------------------------------------------------------------
// K2ex: forward LSTM scan, 64 blocks = 16 batch x 4 slices, 256 threads.
// Thread (u=tid>>2, gq=tid&3) owns gate row r = gq*256 + s*64 + u of W_hh,
// held in 64 float4 VGPRs.  Per step: 256 FMAs vs LDS-broadcast h, shfl
// gate combine, publish 64 h values + release flag, acquire-spin on peers.
// --------------------------------------------------------------------------
__global__ __launch_bounds__(256) void k2ex(
    const float* __restrict__ w_hh,   // [1024][256] fp32 (original layout)
    const float* __restrict__ xpG,    // [2048][1024]
    float* __restrict__ hX,           // [16][128][256]  slot t-1 holds h_t
    int* __restrict__ flags,          // [16][132]  flags[b][t] = #slices that published h_t
    unsigned short* __restrict__ outB)
{
  const int tid = threadIdx.x;
  const int b = blockIdx.x >> 2;
  const int s = blockIdx.x & 3;
  const int u  = tid >> 2;            // unit within slice 0..63
  const int gq = tid & 3;             // gate 0:i 1:f 2:g 3:o
  const int unit = s * 64 + u;        // global hidden unit
  const int r  = gq * 256 + unit;     // gate row in [0,1024)

  // one-time: weights into VGPRs
  float4 wv[64];
  const float4* wrow = (const float4*)(w_hh + (size_t)r * 256);
#pragma unroll
  for (int k = 0; k < 64; ++k) wv[k] = wrow[k];

  __shared__ __align__(16) float hL[256];
  const int lane = tid & 63;
  const int base = lane & ~3;         // first lane of this unit's quad

  float c = 0.f;
  int* flagB = flags + b * 132;
  float* hXb = hX + (size_t)b * 128 * 256;

  for (int t = 0; t < Sq; ++t) {
    // issue xp load early (no dependence on h)
    const float accx = xpG[(size_t)(b * Sq + t) * 1024 + r];

    // obtain h_t into hL
    if (t == 0) {
      hL[tid] = 0.f;
    } else {
      if (tid == 0) {
        while (__hip_atomic_load(flagB + t, __ATOMIC_ACQUIRE,
                                 __HIP_MEMORY_SCOPE_AGENT) < 4) {}
      }
      __syncthreads();
      hL[tid] = __hip_atomic_load(hXb + (t - 1) * 256 + tid, __ATOMIC_RELAXED,
                                  __HIP_MEMORY_SCOPE_AGENT);
    }
    __syncthreads();

    // dot: 256 FMAs, 4 independent chains
    float a0 = 0.f, a1 = 0.f, a2 = 0.f, a3 = 0.f;
#pragma unroll
    for (int k = 0; k < 64; ++k) {
      const float4 h4 = *(const float4*)(hL + 4 * k);
      a0 = fmaf(wv[k].x, h4.x, a0);
      a1 = fmaf(wv[k].y, h4.y, a1);
      a2 = fmaf(wv[k].z, h4.z, a2);
      a3 = fmaf(wv[k].w, h4.w, a3);
    }
    const float pre = accx + (a0 + a1) + (a2 + a3);

    // gate combine: lanes base..base+3 hold i,f,g,o preacts for unit u
    const float vi = __shfl(pre, base + 0);
    const float vf = __shfl(pre, base + 1);
    const float vg = __shfl(pre, base + 2);
    const float vo = __shfl(pre, base + 3);
    const float ig = sigm(vi);
    const float fg = sigm(vf);
    const float gg = tanh_(vg);
    const float og = sigm(vo);
    c = fg * c + ig * gg;
    const float hn = og * tanh_(c);

    // publish h_{t+1}
    if (gq == 0) {
      outB[(size_t)(b * Sq + t) * Ktot + unit] = f2bf(hn);
      if (t + 1 < Sq) {
        __hip_atomic_store(hXb + t * 256 + unit, hn, __ATOMIC_RELAXED,
                           __HIP_MEMORY_SCOPE_AGENT);
      }
    }
    __syncthreads();   // all stores issued & drained before flag (barrier implies vm drain)
    if (tid == 0 && t + 1 < Sq) {
      __hip_atomic_fetch_add(flagB + t + 1, 1, __ATOMIC_RELEASE,
                             __HIP_MEMORY_SCOPE_AGENT);
    }
  }
}

// --------------------------------------------------------------------------
// K3: fc_w fp32 -> bf16.  16,384,000 elems; 4 per thread.
// --------------------------------------------------------------------------
__global__ __launch_bounds__(256) void k3_cvt(const float4* __restrict__ s,
                                              uint2* __restrict__ d)
{
  const int i = blockIdx.x * 256 + threadIdx.x;
  const float4 v = s[i];
  uint2 r;
  r.x = (unsigned)f2bf(v.x) | ((unsigned)f2bf(v.y) << 16);
  r.y = (unsigned)f2bf(v.z) | ((unsigned)f2bf(v.w) << 16);
  d[i] = r;
}

// --------------------------------------------------------------------------
// K4: logits = [2048,512](bf16) x fc_w^T (fc_w [32000,512] bf16, B^T layout)
// + fc_b.  128x128 tile, BK=64, 4 waves, global_load_lds width-16 staging.
// --------------------------------------------------------------------------
__device__ __forceinline__ void load_lds_16(const void* g, void* l) {
  __builtin_amdgcn_global_load_lds(
      (const __attribute__((address_space(1))) unsigned int*)g,
      (__attribute__((address_space(3))) unsigned int*)l, 16, 0, 0);
}

__global__ __launch_bounds__(256) void k4_gemm(
    const unsigned short* __restrict__ A,   // [2048][512] bf16
    const unsigned short* __restrict__ Bm,  // [32000][512] bf16
    const float* __restrict__ fcb,          // [32000]
    float* __restrict__ out)                // [2048][32000]
{
  __shared__ __align__(16) char smem[32768];
  const int tid  = threadIdx.x;
  const int wave = tid >> 6;
  const int lane = tid & 63;
  const int bm = blockIdx.x;      // 0..15  (M tiles)
  const int bn = blockIdx.y;      // 0..249 (N tiles)
  const int wm = (wave >> 1) * 64;
  const int wn = (wave & 1) * 64;
  const int quad = lane >> 4;
  const int r16  = lane & 15;

  f32x4 acc[4][4] = {};

  const unsigned short* Ag = A  + ((size_t)(bm * 128) + (tid >> 3)) * Ktot + (tid & 7) * 8;
  const unsigned short* Bg = Bm + ((size_t)(bn * 128) + (tid >> 3)) * Ktot + (tid & 7) * 8;
  char* AsW = smem + wave * 1024;
  char* BsW = smem + 16384 + wave * 1024;

  for (int kt = 0; kt < 8; ++kt) {
    const int k0 = kt * 64;
#pragma unroll
    for (int r = 0; r < 4; ++r) {
      load_lds_16(Ag + (size_t)r * 32 * Ktot + k0, AsW + r * 4096);
      load_lds_16(Bg + (size_t)r * 32 * Ktot + k0, BsW + r * 4096);
    }
    __syncthreads();
#pragma unroll
    for (int kk = 0; kk < 2; ++kk) {
      bf16x8 af[4], bfr[4];
#pragma unroll
      for (int i = 0; i < 4; ++i) {
        const int rowA = wm + i * 16 + r16;
        af[i] = *(const bf16x8*)(smem + rowA * 128 + kk * 64 + quad * 16);
        const int rowB = wn + i * 16 + r16;
        bfr[i] = *(const bf16x8*)(smem + 16384 + rowB * 128 + kk * 64 + quad * 16);
      }
#pragma unroll
      for (int i = 0; i < 4; ++i)
#pragma unroll
        for (int j = 0; j < 4; ++j)
          acc[i][j] = __builtin_amdgcn_mfma_f32_16x16x32_bf16(af[i], bfr[j], acc[i][j], 0, 0, 0);
    }
    __syncthreads();
  }

#pragma unroll
  for (int j = 0; j < 4; ++j) {
    const int col = bn * 128 + wn + j * 16 + r16;
    const float bias = fcb[col];
#pragma unroll
    for (int i = 0; i < 4; ++i) {
      const int row0 = bm * 128 + wm + i * 16 + quad * 4;
#pragma unroll
      for (int r = 0; r < 4; ++r) {
        out[(size_t)(row0 + r) * Vv + col] = acc[i][j][r] + bias;
      }
    }
  }
}

// --------------------------------------------------------------------------
extern "C" void kernel_launch(void* const* d_in, const int* in_sizes, int n_in,
                              void* d_out, int out_size, void* d_ws, size_t ws_size,
                              hipStream_t stream) {
  const int*   x      = (const int*)d_in[0];
  const float* embed  = (const float*)d_in[1];
  const float* w_ih_f = (const float*)d_in[2];
  const float* w_hh_f = (const float*)d_in[3];
  const float* b_ih_f = (const float*)d_in[4];
  const float* b_hh_f = (const float*)d_in[5];
  const float* w_ih_b = (const float*)d_in[6];
  // d_in[7] = w_hh_b: unused (backward direction is a zero-state single step)
  const float* b_ih_b = (const float*)d_in[8];
  const float* b_hh_b = (const float*)d_in[9];
  const float* fc_w   = (const float*)d_in[10];
  const float* fc_b   = (const float*)d_in[11];
  float* out = (float*)d_out;

  // Workspace layout (peak 45.4 MB; hX overlays wPackF/wPackB which are
  // dead after k1):
  char* ws = (char*)d_ws;
  float4* wPackF = (float4*)(ws + 0x000000);            // 1 MB   (k0 w, k1 r)
  float4* wPackB = (float4*)(ws + 0x100000);            // 1 MB   (k0 w, k1 r)
  float*  hX     = (float*)(ws + 0x000000);             // 2 MB   (k2 only)
  float*  xpG    = (float*)(ws + 0x200000);             // 8 MB   (k1 w, k2 r)
  float4* biasF  = (float4*)(ws + 0xA00000);            // 4 KB
  float4* biasB  = (float4*)(ws + 0xA01000);            // 4 KB
  int*    flags  = (int*)(ws + 0xA02000);               // 8.25 KB (init w, k2 rw)
  unsigned short* outB = (unsigned short*)(ws + 0xA05000);   // 2 MB [2048][512]
  unsigned short* fcwB = (unsigned short*)(ws + 0xC05000);   // 31.25 MiB

  k_init<<<1, 256, 0, stream>>>(flags);
  k0_pack<<<dim3(256, 2), 256, 0, stream>>>(w_ih_f, w_ih_b,
                                            b_ih_f, b_hh_f, b_ih_b, b_hh_b,
                                            wPackF, wPackB, biasF, biasB);
  k3_cvt<<<16000, 256, 0, stream>>>((const float4*)fc_w, (uint2*)fcwB);
  k1_embproj<<<dim3(128, 2), 256, 0, stream>>>(x, embed, wPackF, wPackB,
                                               biasF, biasB, xpG, outB);
  k2ex<<<64, 256, 0, stream>>>(w_hh_f, xpG, hX, flags, outB);
  k4_gemm<<<dim3(16, 250), 256, 0, stream>>>(outB, fcwB, fc_b, out);
}